// Round 18
// baseline (101.243 us; speedup 1.0000x reference)
//
#include <hip/hip_runtime.h>

#define NB 32
#define CIN 64
#define TT 300
#define VV 25
#define CO 128
#define NSLICE 9600
#define NBLK2 4800            // blocks: 2 waves each, 2 t-slices per block
#define NBUCKET 64
#define EPSV 1e-5f
#define SCALEV 0.17677669529663687f   // 1/sqrt(32), folded into twA/tbD in K0
#define NRED (NB*TT*VV)               // 240000

using bf16x8 = __attribute__((ext_vector_type(8))) short;
using f32x4  = __attribute__((ext_vector_type(4))) float;
using f32x16 = __attribute__((ext_vector_type(16))) float;
typedef unsigned short ushort_t;

__device__ __forceinline__ unsigned short f2bf(float f) {
    union { float f; unsigned u; } v; v.f = f;
    unsigned u = v.u;
    return (unsigned short)((u + 0x7fffu + ((u >> 16) & 1u)) >> 16);   // RNE
}
__device__ __forceinline__ unsigned pkbf(float a, float b) {
    unsigned r;
    asm("v_cvt_pk_bf16_f32 %0, %1, %2" : "=v"(r) : "v"(a), "v"(b));
    return r;
}
// two-output permlane32_swap (round-4 lesson: must model BOTH results)
__device__ __forceinline__ void plswap(unsigned &a, unsigned &b) {
#if __has_builtin(__builtin_amdgcn_permlane32_swap)
    auto r = __builtin_amdgcn_permlane32_swap(a, b, false, false);
    a = r[0]; b = r[1];
#else
    unsigned a2, b2;
    asm("v_permlane32_swap_b32 %0, %1" : "=v"(a2), "=v"(b2) : "0"(a), "1"(b));
    a = a2; b = b2;
#endif
}
__device__ __forceinline__ float xhalf_sum(float x) {
    unsigned a = __float_as_uint(x), b = __float_as_uint(x);
    plswap(a, b);
    return __uint_as_float(a) + __uint_as_float(b);
}
__device__ __forceinline__ float xhalf_max(float x) {
    unsigned a = __float_as_uint(x), b = __float_as_uint(x);
    plswap(a, b);
    return fmaxf(__uint_as_float(a), __uint_as_float(b));
}
__device__ __forceinline__ f32x16 splat16(float v) {
    f32x16 r;
    #pragma unroll
    for (int i = 0; i < 16; ++i) r[i] = v;
    return r;
}
// D-tile (col=lane&31, row=(r&3)+8*(r>>2)+4*(lane>>5)) -> A/B frags, k=D rows
__device__ __forceinline__ void rearr(const f32x16& d, bf16x8& f0, bf16x8& f1) {
    unsigned u0 = pkbf(d[0],  d[1]),  u1 = pkbf(d[2],  d[3]);
    unsigned u2 = pkbf(d[4],  d[5]),  u3 = pkbf(d[6],  d[7]);
    unsigned u4 = pkbf(d[8],  d[9]),  u5 = pkbf(d[10], d[11]);
    unsigned u6 = pkbf(d[12], d[13]), u7 = pkbf(d[14], d[15]);
    plswap(u0, u2); plswap(u1, u3); plswap(u4, u6); plswap(u5, u7);
    union { unsigned u[4]; bf16x8 v; } c0, c1;
    c0.u[0] = u0; c0.u[1] = u1; c0.u[2] = u2; c0.u[3] = u3;
    c1.u[0] = u4; c1.u[1] = u5; c1.u[2] = u6; c1.u[3] = u7;
    f0 = c0.v; f1 = c1.v;
}

// ---------------------------------------------------------------------------
// K0: pre-swizzle weights into 32x32x16 fragment order + bias D-images,
// zero bsum/bsq (fused memset). SCALEV folded into twA/tbD (verified r16/17).
// Grid 64 x 256. (structure verified rounds 13/14/16/17)
// ---------------------------------------------------------------------------
__global__ void agc_k0(const float* __restrict__ tw, const float* __restrict__ pw,
                       const float* __restrict__ gw,
                       const float* __restrict__ tb, const float* __restrict__ pb,
                       ushort_t* __restrict__ twA, ushort_t* __restrict__ pwA,
                       ushort_t* __restrict__ gwB,
                       float* __restrict__ tbD, float* __restrict__ pbD,
                       float* __restrict__ zws)
{
    int e = blockIdx.x*256 + threadIdx.x;
    if (e < 16384) zws[e] = 0.f;          // bsum+bsq = 2*64*128 floats
    if (e < 12288) {
        int j = e & 7, l = (e >> 3) & 63, ks = (e >> 9) & 3;
        int c = ks*16 + (l >> 5)*8 + j;
        int n = l & 31;
        int grp = e >> 11;          // 0: tw, 1: pw, 2..5: gw ot=grp-2
        if (grp == 0)      twA[e]        = f2bf(tw[n*CIN + c] * SCALEV);
        else if (grp == 1) pwA[e - 2048] = f2bf(pw[n*CIN + c]);
        else               gwB[e - 4096] = f2bf(gw[(grp - 2)*32*CIN + n*CIN + c]);
    } else if (e < 14336) {
        int e2 = e - 12288;
        int r = e2 & 15, l = (e2 >> 4) & 63;
        int i = (r & 3) + 8*(r >> 2) + 4*(l >> 5);
        if (e2 < 1024) tbD[e2]        = tb[i] * SCALEV;
        else           pbD[e2 - 1024] = pb[i];
    }
}

// ---------------------------------------------------------------------------
// K1: r17 per-wave pipeline VERBATIM, re-grained to 2-wave / 2-slice blocks
// (4800 blocks x 128 threads). Same total work, no duplication; smaller
// barrier convoys + finer block granularity -> more resident blocks/CU.
// float2 staging/stores (50-float window is not float4-aligned).
// 128 threads, default __launch_bounds__ ONLY (r7/r8/r12 lesson).
// LDS: xs[64][50] f32 (12800 B, dead after B1) overlaid by outS[64][60] f32
//      (15360 B); red[256] f32 at +15360 -> 16384 B total.
// ---------------------------------------------------------------------------
__global__ __launch_bounds__(128) void agc_k1(
    const float* __restrict__ x, const float* __restrict__ gb,
    const ushort_t* __restrict__ twA, const ushort_t* __restrict__ pwA,
    const ushort_t* __restrict__ gwB,
    const float* __restrict__ tbD, const float* __restrict__ pbD,
    float* __restrict__ out, float* __restrict__ bsum, float* __restrict__ bsq)
{
    __shared__ __align__(16) float lds[4096];     // 16384 B
    float* xs   = lds;            // [64][50]
    float* outS = lds;            // [64][60] overlay (live after B1)
    float* red  = lds + 3840;     // [0..127] sum, [128..255] sumsq

    const int tid  = threadIdx.x;
    const int lane = tid & 63;
    const int wid  = tid >> 6;    // 0..1 (slice in block)
    const int l31  = lane & 31;
    const int h    = lane >> 5;

    const int blk = blockIdx.x;
    const int grp = (blk & 7) * (NBLK2/8) + (blk >> 3);  // XCD swizzle
    const int b   = grp / 150;
    const int j2  = grp - b*150;      // block covers t = 2*j2, 2*j2+1

    red[tid] = 0.f;
    red[tid + 128] = 0.f;

    // ---- stage x slab: 64 ch x 50 v, coalesced float2 ----
    const float2* gx2 = (const float2*)x + (size_t)b*240000 + (size_t)j2*25;
    for (int e = tid; e < 1600; e += 128) {
        int c = e / 25, q = e - c*25;
        *(float2*)&xs[c*50 + q*2] = gx2[(size_t)c*3750 + q];
    }
    __syncthreads();                                     // B0

    // ---- x fragments from LDS ----
    const int vcl  = l31 < VV ? l31 : VV-1;       // clamp dup (pad col)
    const int colx = wid*25 + vcl;
    bf16x8 xf[4];
    #pragma unroll
    for (int ks = 0; ks < 4; ++ks) {
        float v[8];
        #pragma unroll
        for (int j = 0; j < 8; ++j)
            v[j] = xs[(ks*16 + h*8 + j)*50 + colx];
        union { unsigned u[4]; bf16x8 f; } c;
        c.u[0] = pkbf(v[0], v[1]); c.u[1] = pkbf(v[2], v[3]);
        c.u[2] = pkbf(v[4], v[5]); c.u[3] = pkbf(v[6], v[7]);
        xf[ks] = c.f;
    }
    __syncthreads();                                     // B1 (xs dead)

    // ---- th = (s*tw)@xT + s*tb, ph = pw@xT + pb  (D: col=v, rows=i) ----
    f32x16 th, ph;
    #pragma unroll
    for (int r = 0; r < 4; ++r) {
        f32x4 bb = ((const f32x4*)(tbD + lane*16))[r];
        th[4*r+0] = bb[0]; th[4*r+1] = bb[1]; th[4*r+2] = bb[2]; th[4*r+3] = bb[3];
        f32x4 pp = ((const f32x4*)(pbD + lane*16))[r];
        ph[4*r+0] = pp[0]; ph[4*r+1] = pp[1]; ph[4*r+2] = pp[2]; ph[4*r+3] = pp[3];
    }
    #pragma unroll
    for (int ks = 0; ks < 4; ++ks) {
        bf16x8 twf = *(const bf16x8*)(twA + (ks*64 + lane)*8);
        th = __builtin_amdgcn_mfma_f32_32x32x16_bf16(twf, xf[ks], th, 0, 0, 0);
        bf16x8 pwf = *(const bf16x8*)(pwA + (ks*64 + lane)*8);
        ph = __builtin_amdgcn_mfma_f32_32x32x16_bf16(pwf, xf[ks], ph, 0, 0, 0);
    }

    // ---- ST = ph^T_frag (A, rows w) x th_frag (B, cols v); k = i = 32 ----
    bf16x8 thf0, thf1, phf0, phf1;
    rearr(th, thf0, thf1);
    rearr(ph, phf0, phf1);
    f32x16 st = splat16(0.f);
    st = __builtin_amdgcn_mfma_f32_32x32x16_bf16(phf0, thf0, st, 0, 0, 0);
    st = __builtin_amdgcn_mfma_f32_32x32x16_bf16(phf1, thf1, st, 0, 0, 0);

    // ---- softmax over w, on st in place (regs 0..11 always; 12 iff h==0) --
    float m = fmaxf(fmaxf(fmaxf(st[0], st[1]), fmaxf(st[2], st[3])),
                    fmaxf(fmaxf(st[4], st[5]), fmaxf(st[6], st[7])));
    m = fmaxf(m, fmaxf(fmaxf(st[8], st[9]), fmaxf(st[10], st[11])));
    float s12 = h ? -3.4e38f : st[12];
    m = fmaxf(m, s12);
    m = xhalf_max(m);
    f32x16 pd;
    #pragma unroll
    for (int r = 0; r < 12; ++r) pd[r] = __expf(st[r] - m);
    pd[12] = h ? 0.f : __expf(st[12] - m);
    pd[13] = 0.f; pd[14] = 0.f; pd[15] = 0.f;
    float sum = ((pd[0]+pd[1]) + (pd[2]+pd[3])) + ((pd[4]+pd[5]) + (pd[6]+pd[7]))
              + ((pd[8]+pd[9]) + (pd[10]+pd[11])) + pd[12];
    sum = xhalf_sum(sum);
    float rinv;
    asm("v_rcp_f32 %0, %1" : "=v"(rinv) : "v"(sum));
    #pragma unroll
    for (int r = 0; r < 13; ++r) pd[r] *= rinv;
    bf16x8 pf0, pf1;
    rearr(pd, pf0, pf1);   // A-frag: row v = l31, k = w

    // ---- one output tile: g-proj + PV + b128 LDS stage + stats ----
    auto process_ot = [&](int ot) {
        f32x16 gd = splat16(0.f);
        #pragma unroll
        for (int ks = 0; ks < 4; ++ks) {
            bf16x8 gf = *(const bf16x8*)(gwB + ((ot*4 + ks)*64 + lane)*8);
            gd = __builtin_amdgcn_mfma_f32_32x32x16_bf16(xf[ks], gf, gd, 0, 0, 0);
        }
        bf16x8 gf0, gf1;
        rearr(gd, gf0, gf1);            // B-frag: col o = l31, k = w
        f32x16 od = splat16(gb[ot*32 + l31]);   // softmax rows sum to 1
        od = __builtin_amdgcn_mfma_f32_32x32x16_bf16(pf0, gf0, od, 0, 0, 0);
        od = __builtin_amdgcn_mfma_f32_32x32x16_bf16(pf1, gf1, od, 0, 0, 0);

        const int o_loc = (ot & 1)*32 + l31;    // row in phase buffer
        float* base = &outS[o_loc*60 + wid*28];
        float ss = 0.f, qq = 0.f;
        #pragma unroll
        for (int q = 0; q < 3; ++q) {            // quads: v = 8q + 4h .. +3
            f32x4 qv = {od[4*q], od[4*q+1], od[4*q+2], od[4*q+3]};
            *(f32x4*)&base[8*q + 4*h] = qv;
            ss += (qv[0] + qv[1]) + (qv[2] + qv[3]);
            qq = fmaf(qv[0], qv[0], qq); qq = fmaf(qv[1], qv[1], qq);
            qq = fmaf(qv[2], qv[2], qq); qq = fmaf(qv[3], qv[3], qq);
        }
        if (!h) {                                 // v = 24 (reg 12)
            base[24] = od[12];
            ss += od[12]; qq = fmaf(od[12], od[12], qq);
        }
        ss = xhalf_sum(ss); qq = xhalf_sum(qq);
        if (lane < 32) {
            atomicAdd(&red[ot*32 + l31], ss);
            atomicAdd(&red[128 + ot*32 + l31], qq);
        }
    };

    // readback: gather 2 scalars (col = v + 3*(v/25)), float2 store
    auto readback = [&](int p) {
        for (int e = tid; e < 1600; e += 128) {
            int o_loc = e / 25, q2 = e - o_loc*25;
            int v0 = 2*q2;
            const float* row = &outS[o_loc*60];
            float tmp[2];
            #pragma unroll
            for (int jj = 0; jj < 2; ++jj) {
                int v = v0 + jj;
                int sdx = (v*41) >> 10;           // v/25 for v<50
                tmp[jj] = row[v + 3*sdx];
            }
            float2 val;
            val.x = tmp[0]; val.y = tmp[1];
            ((float2*)out)[(size_t)(b*CO + p*64 + o_loc)*3750 + (size_t)j2*25 + q2] = val;
        }
    };

    process_ot(0); process_ot(1);
    __syncthreads();                                     // B2
    readback(0);
    __syncthreads();                                     // B3
    process_ot(2); process_ot(3);
    __syncthreads();                                     // B4
    readback(1);
    if (tid < CO) {
        int bkt = blk & (NBUCKET-1);
        atomicAdd(&bsum[bkt*CO + tid], red[tid]);
        atomicAdd(&bsq [bkt*CO + tid], red[128 + tid]);
    }
}

// ---------------------------------------------------------------------------
// K2: fold buckets -> per-channel scale/shift  (1 block, 128 threads)
// ---------------------------------------------------------------------------
__global__ void agc_k2(const float* __restrict__ bsum, const float* __restrict__ bsq,
                       const float* __restrict__ gamma, const float* __restrict__ beta,
                       float* __restrict__ scl, float* __restrict__ shf)
{
    const int o = threadIdx.x;
    float s = 0.f, q = 0.f;
    for (int k = 0; k < NBUCKET; ++k) { s += bsum[k*CO + o]; q += bsq[k*CO + o]; }
    float mean = s / (float)NRED;
    float var  = q / (float)NRED - mean*mean;
    float rstd = rsqrtf(var + EPSV);
    float sc = gamma[o] * rstd;
    scl[o] = sc;
    shf[o] = beta[o] - mean * sc;
}

// ---------------------------------------------------------------------------
// K3: in-place normalize d_out, float4 coalesced (L3-resident)
// ---------------------------------------------------------------------------
__global__ __launch_bounds__(256) void agc_k3(
    float* __restrict__ out, const float* __restrict__ scl, const float* __restrict__ shf)
{
    const int n4 = NB*CO*TT*VV/4;
    float4* p = (float4*)out;
    for (int i = blockIdx.x*blockDim.x + threadIdx.x; i < n4; i += gridDim.x*blockDim.x) {
        int ch = (i / (TT*VV/4)) & (CO-1);
        float4 v = p[i];
        float sc = scl[ch], sh = shf[ch];
        v.x = fmaf(v.x, sc, sh);
        v.y = fmaf(v.y, sc, sh);
        v.z = fmaf(v.z, sc, sh);
        v.w = fmaf(v.w, sc, sh);
        p[i] = v;
    }
}

extern "C" void kernel_launch(void* const* d_in, const int* in_sizes, int n_in,
                              void* d_out, int out_size, void* d_ws, size_t ws_size,
                              hipStream_t stream) {
    const float* x     = (const float*)d_in[0];
    const float* tw    = (const float*)d_in[1];
    const float* tbb   = (const float*)d_in[2];
    const float* pw    = (const float*)d_in[3];
    const float* pbb   = (const float*)d_in[4];
    const float* gw    = (const float*)d_in[5];
    const float* gbb   = (const float*)d_in[6];
    const float* gamma = (const float*)d_in[7];
    const float* beta  = (const float*)d_in[8];
    float* out = (float*)d_out;
    float* ws  = (float*)d_ws;

    float* bsum = ws;                          // [64][128]
    float* bsq  = ws + NBUCKET*CO;             // [64][128]
    float* scl  = ws + 2*NBUCKET*CO;           // [128]
    float* shf  = ws + 2*NBUCKET*CO + CO;      // [128]
    ushort_t* twA = (ushort_t*)(ws + 2*NBUCKET*CO + 2*CO);   // 2048 bf16
    ushort_t* pwA = twA + 2048;                               // 2048 bf16
    ushort_t* gwB = twA + 4096;                               // 8192 bf16
    float* tbD = (float*)(gwB + 8192);                        // 1024 f32
    float* pbD = tbD + 1024;                                  // 1024 f32

    agc_k0<<<64, 256, 0, stream>>>(tw, pw, gw, tbb, pbb, twA, pwA, gwB, tbD, pbD, ws);
    agc_k1<<<NBLK2, 128, 0, stream>>>(x, gbb, twA, pwA, gwB, tbD, pbD, out, bsum, bsq);
    agc_k2<<<1, CO, 0, stream>>>(bsum, bsq, gamma, beta, scl, shf);
    agc_k3<<<2048, 256, 0, stream>>>(out, scl, shf);
}

// Round 19
// 93.575 us; speedup vs baseline: 1.0819x; 1.0819x over previous
//
#include <hip/hip_runtime.h>

#define NB 32
#define CIN 64
#define TT 300
#define VV 25
#define CO 128
#define NSLICE 9600
#define NBLK 2400
#define NBUCKET 64
#define EPSV 1e-5f
#define SCALEV 0.17677669529663687f   // 1/sqrt(32), folded into twA/tbD in K0
#define NRED (NB*TT*VV)               // 240000

using bf16x8 = __attribute__((ext_vector_type(8))) short;
using f32x4  = __attribute__((ext_vector_type(4))) float;
using f32x16 = __attribute__((ext_vector_type(16))) float;
typedef unsigned short ushort_t;

__device__ __forceinline__ unsigned short f2bf(float f) {
    union { float f; unsigned u; } v; v.f = f;
    unsigned u = v.u;
    return (unsigned short)((u + 0x7fffu + ((u >> 16) & 1u)) >> 16);   // RNE
}
__device__ __forceinline__ unsigned pkbf(float a, float b) {
    unsigned r;
    asm("v_cvt_pk_bf16_f32 %0, %1, %2" : "=v"(r) : "v"(a), "v"(b));
    return r;
}
// two-output permlane32_swap (round-4 lesson: must model BOTH results)
__device__ __forceinline__ void plswap(unsigned &a, unsigned &b) {
#if __has_builtin(__builtin_amdgcn_permlane32_swap)
    auto r = __builtin_amdgcn_permlane32_swap(a, b, false, false);
    a = r[0]; b = r[1];
#else
    unsigned a2, b2;
    asm("v_permlane32_swap_b32 %0, %1" : "=v"(a2), "=v"(b2) : "0"(a), "1"(b));
    a = a2; b = b2;
#endif
}
__device__ __forceinline__ float xhalf_sum(float x) {
    unsigned a = __float_as_uint(x), b = __float_as_uint(x);
    plswap(a, b);
    return __uint_as_float(a) + __uint_as_float(b);
}
__device__ __forceinline__ float xhalf_max(float x) {
    unsigned a = __float_as_uint(x), b = __float_as_uint(x);
    plswap(a, b);
    return fmaxf(__uint_as_float(a), __uint_as_float(b));
}
__device__ __forceinline__ f32x16 splat16(float v) {
    f32x16 r;
    #pragma unroll
    for (int i = 0; i < 16; ++i) r[i] = v;
    return r;
}
// D-tile (col=lane&31, row=(r&3)+8*(r>>2)+4*(lane>>5)) -> A/B frags, k=D rows
__device__ __forceinline__ void rearr(const f32x16& d, bf16x8& f0, bf16x8& f1) {
    unsigned u0 = pkbf(d[0],  d[1]),  u1 = pkbf(d[2],  d[3]);
    unsigned u2 = pkbf(d[4],  d[5]),  u3 = pkbf(d[6],  d[7]);
    unsigned u4 = pkbf(d[8],  d[9]),  u5 = pkbf(d[10], d[11]);
    unsigned u6 = pkbf(d[12], d[13]), u7 = pkbf(d[14], d[15]);
    plswap(u0, u2); plswap(u1, u3); plswap(u4, u6); plswap(u5, u7);
    union { unsigned u[4]; bf16x8 v; } c0, c1;
    c0.u[0] = u0; c0.u[1] = u1; c0.u[2] = u2; c0.u[3] = u3;
    c1.u[0] = u4; c1.u[1] = u5; c1.u[2] = u6; c1.u[3] = u7;
    f0 = c0.v; f1 = c1.v;
}

// async global->LDS, 16B per lane; LDS dest must be wave-uniform base +
// lane*16 (our staging mapping satisfies this: dest = xs + e*16B, e=tid+k*256)
__device__ __forceinline__ void g2l16(const float4* g, float* l) {
    __builtin_amdgcn_global_load_lds(
        (const __attribute__((address_space(1))) unsigned*)g,
        (__attribute__((address_space(3))) unsigned*)l, 16, 0, 0);
}

// ---------------------------------------------------------------------------
// K0: pre-swizzle weights into 32x32x16 fragment order + bias D-images,
// zero bsum/bsq (fused memset). SCALEV folded into twA/tbD (verified r16/17).
// Grid 64 x 256. (structure verified rounds 13/14/16/17)
// ---------------------------------------------------------------------------
__global__ void agc_k0(const float* __restrict__ tw, const float* __restrict__ pw,
                       const float* __restrict__ gw,
                       const float* __restrict__ tb, const float* __restrict__ pb,
                       ushort_t* __restrict__ twA, ushort_t* __restrict__ pwA,
                       ushort_t* __restrict__ gwB,
                       float* __restrict__ tbD, float* __restrict__ pbD,
                       float* __restrict__ zws)
{
    int e = blockIdx.x*256 + threadIdx.x;
    if (e < 16384) zws[e] = 0.f;          // bsum+bsq = 2*64*128 floats
    if (e < 12288) {
        int j = e & 7, l = (e >> 3) & 63, ks = (e >> 9) & 3;
        int c = ks*16 + (l >> 5)*8 + j;
        int n = l & 31;
        int grp = e >> 11;          // 0: tw, 1: pw, 2..5: gw ot=grp-2
        if (grp == 0)      twA[e]        = f2bf(tw[n*CIN + c] * SCALEV);
        else if (grp == 1) pwA[e - 2048] = f2bf(pw[n*CIN + c]);
        else               gwB[e - 4096] = f2bf(gw[(grp - 2)*32*CIN + n*CIN + c]);
    } else if (e < 14336) {
        int e2 = e - 12288;
        int r = e2 & 15, l = (e2 >> 4) & 63;
        int i = (r & 3) + 8*(r >> 2) + 4*(l >> 5);
        if (e2 < 1024) tbD[e2]        = tb[i] * SCALEV;
        else           pbD[e2 - 1024] = pb[i];
    }
}

// ---------------------------------------------------------------------------
// K1: round-17 verified pipeline VERBATIM except the x staging uses async
// global_load_lds (width=16): no VGPR round-trip, loads stream until B0's
// natural vmcnt(0) drain. LDS dest is linear (e*16B) = wave-uniform base +
// lane*16, satisfying the HW constraint (m104). 256 threads, default
// __launch_bounds__ ONLY (r7/r8/r12 lesson).
// LDS: xs[64][100] overlaid by outS[64][116]; red[256] at +7424.
// ---------------------------------------------------------------------------
__global__ __launch_bounds__(256) void agc_k1(
    const float* __restrict__ x, const float* __restrict__ gb,
    const ushort_t* __restrict__ twA, const ushort_t* __restrict__ pwA,
    const ushort_t* __restrict__ gwB,
    const float* __restrict__ tbD, const float* __restrict__ pbD,
    float* __restrict__ out, float* __restrict__ bsum, float* __restrict__ bsq)
{
    __shared__ __align__(16) float lds[7680];     // 30720 B
    float* xs   = lds;            // [64][100]
    float* outS = lds;            // [64][116] overlay (live after B1)
    float* red  = lds + 7424;     // [0..127] sum, [128..255] sumsq

    const int tid  = threadIdx.x;
    const int lane = tid & 63;
    const int wid  = tid >> 6;
    const int l31  = lane & 31;
    const int h    = lane >> 5;

    const int blk = blockIdx.x;
    const int grp = (blk & 7) * (NBLK/8) + (blk >> 3);   // XCD swizzle
    const int b   = grp / 75;
    const int j4  = grp - b*75;       // block covers t = 4*j4 .. 4*j4+3

    red[tid] = 0.f;

    // ---- stage x slab: 64 ch x 100 v, async global_load_lds x4 ----
    const float4* gx = (const float4*)x + (size_t)b*120000 + (size_t)j4*25;
    for (int e = tid; e < 1600; e += 256) {
        int c = e / 25, q = e - c*25;
        g2l16(&gx[(size_t)c*1875 + q], &xs[e*4]);
    }
    __syncthreads();                                     // B0 (vmcnt(0) drain)

    // ---- x fragments from LDS (2-way bank aliasing = free) ----
    const int vcl  = l31 < VV ? l31 : VV-1;       // clamp dup (pad col)
    const int colx = wid*25 + vcl;
    bf16x8 xf[4];
    #pragma unroll
    for (int ks = 0; ks < 4; ++ks) {
        float v[8];
        #pragma unroll
        for (int j = 0; j < 8; ++j)
            v[j] = xs[(ks*16 + h*8 + j)*100 + colx];
        union { unsigned u[4]; bf16x8 f; } c;
        c.u[0] = pkbf(v[0], v[1]); c.u[1] = pkbf(v[2], v[3]);
        c.u[2] = pkbf(v[4], v[5]); c.u[3] = pkbf(v[6], v[7]);
        xf[ks] = c.f;
    }
    __syncthreads();                                     // B1 (xs dead)

    // ---- th = (s*tw)@xT + s*tb, ph = pw@xT + pb  (D: col=v, rows=i) ----
    f32x16 th, ph;
    #pragma unroll
    for (int r = 0; r < 4; ++r) {
        f32x4 bb = ((const f32x4*)(tbD + lane*16))[r];
        th[4*r+0] = bb[0]; th[4*r+1] = bb[1]; th[4*r+2] = bb[2]; th[4*r+3] = bb[3];
        f32x4 pp = ((const f32x4*)(pbD + lane*16))[r];
        ph[4*r+0] = pp[0]; ph[4*r+1] = pp[1]; ph[4*r+2] = pp[2]; ph[4*r+3] = pp[3];
    }
    #pragma unroll
    for (int ks = 0; ks < 4; ++ks) {
        bf16x8 twf = *(const bf16x8*)(twA + (ks*64 + lane)*8);
        th = __builtin_amdgcn_mfma_f32_32x32x16_bf16(twf, xf[ks], th, 0, 0, 0);
        bf16x8 pwf = *(const bf16x8*)(pwA + (ks*64 + lane)*8);
        ph = __builtin_amdgcn_mfma_f32_32x32x16_bf16(pwf, xf[ks], ph, 0, 0, 0);
    }

    // ---- ST = ph^T_frag (A, rows w) x th_frag (B, cols v); k = i = 32 ----
    bf16x8 thf0, thf1, phf0, phf1;
    rearr(th, thf0, thf1);
    rearr(ph, phf0, phf1);
    f32x16 st = splat16(0.f);
    st = __builtin_amdgcn_mfma_f32_32x32x16_bf16(phf0, thf0, st, 0, 0, 0);
    st = __builtin_amdgcn_mfma_f32_32x32x16_bf16(phf1, thf1, st, 0, 0, 0);

    // ---- softmax over w, on st in place (regs 0..11 always; 12 iff h==0) --
    float m = fmaxf(fmaxf(fmaxf(st[0], st[1]), fmaxf(st[2], st[3])),
                    fmaxf(fmaxf(st[4], st[5]), fmaxf(st[6], st[7])));
    m = fmaxf(m, fmaxf(fmaxf(st[8], st[9]), fmaxf(st[10], st[11])));
    float s12 = h ? -3.4e38f : st[12];
    m = fmaxf(m, s12);
    m = xhalf_max(m);
    f32x16 pd;
    #pragma unroll
    for (int r = 0; r < 12; ++r) pd[r] = __expf(st[r] - m);
    pd[12] = h ? 0.f : __expf(st[12] - m);
    pd[13] = 0.f; pd[14] = 0.f; pd[15] = 0.f;
    float sum = ((pd[0]+pd[1]) + (pd[2]+pd[3])) + ((pd[4]+pd[5]) + (pd[6]+pd[7]))
              + ((pd[8]+pd[9]) + (pd[10]+pd[11])) + pd[12];
    sum = xhalf_sum(sum);
    float rinv;
    asm("v_rcp_f32 %0, %1" : "=v"(rinv) : "v"(sum));
    #pragma unroll
    for (int r = 0; r < 13; ++r) pd[r] *= rinv;
    bf16x8 pf0, pf1;
    rearr(pd, pf0, pf1);   // A-frag: row v = l31, k = w

    // ---- one output tile: g-proj + PV + b128 LDS stage + stats ----
    auto process_ot = [&](int ot) {
        f32x16 gd = splat16(0.f);
        #pragma unroll
        for (int ks = 0; ks < 4; ++ks) {
            bf16x8 gf = *(const bf16x8*)(gwB + ((ot*4 + ks)*64 + lane)*8);
            gd = __builtin_amdgcn_mfma_f32_32x32x16_bf16(xf[ks], gf, gd, 0, 0, 0);
        }
        bf16x8 gf0, gf1;
        rearr(gd, gf0, gf1);            // B-frag: col o = l31, k = w
        f32x16 od = splat16(gb[ot*32 + l31]);   // softmax rows sum to 1
        od = __builtin_amdgcn_mfma_f32_32x32x16_bf16(pf0, gf0, od, 0, 0, 0);
        od = __builtin_amdgcn_mfma_f32_32x32x16_bf16(pf1, gf1, od, 0, 0, 0);

        const int o_loc = (ot & 1)*32 + l31;    // row in phase buffer
        float* base = &outS[o_loc*116 + wid*28];
        float ss = 0.f, qq = 0.f;
        #pragma unroll
        for (int q = 0; q < 3; ++q) {            // quads: v = 8q + 4h .. +3
            f32x4 qv = {od[4*q], od[4*q+1], od[4*q+2], od[4*q+3]};
            *(f32x4*)&base[8*q + 4*h] = qv;
            ss += (qv[0] + qv[1]) + (qv[2] + qv[3]);
            qq = fmaf(qv[0], qv[0], qq); qq = fmaf(qv[1], qv[1], qq);
            qq = fmaf(qv[2], qv[2], qq); qq = fmaf(qv[3], qv[3], qq);
        }
        if (!h) {                                 // v = 24 (reg 12)
            base[24] = od[12];
            ss += od[12]; qq = fmaf(od[12], od[12], qq);
        }
        ss = xhalf_sum(ss); qq = xhalf_sum(qq);
        if (lane < 32) {
            atomicAdd(&red[ot*32 + l31], ss);
            atomicAdd(&red[128 + ot*32 + l31], qq);
        }
    };

    // readback: gather 4 scalars (addr = o*116 + v + 3*(v/25)), float4 store
    auto readback = [&](int p) {
        for (int e = tid; e < 1600; e += 256) {
            int o_loc = e / 25, q2 = e - o_loc*25;
            int v0 = 4*q2;
            const float* row = &outS[o_loc*116];
            float tmp[4];
            #pragma unroll
            for (int jj = 0; jj < 4; ++jj) {
                int v = v0 + jj;
                int sdx = (v*41) >> 10;           // v/25 for v<100
                tmp[jj] = row[v + 3*sdx];
            }
            float4 val;
            val.x = tmp[0]; val.y = tmp[1]; val.z = tmp[2]; val.w = tmp[3];
            ((float4*)out)[(size_t)(b*CO + p*64 + o_loc)*1875 + (size_t)j4*25 + q2] = val;
        }
    };

    process_ot(0); process_ot(1);
    __syncthreads();                                     // B2
    readback(0);
    __syncthreads();                                     // B3
    process_ot(2); process_ot(3);
    __syncthreads();                                     // B4
    readback(1);
    if (tid < CO) {
        int bkt = blk & (NBUCKET-1);
        atomicAdd(&bsum[bkt*CO + tid], red[tid]);
        atomicAdd(&bsq [bkt*CO + tid], red[128 + tid]);
    }
}

// ---------------------------------------------------------------------------
// K2: fold buckets -> per-channel scale/shift  (1 block, 128 threads)
// ---------------------------------------------------------------------------
__global__ void agc_k2(const float* __restrict__ bsum, const float* __restrict__ bsq,
                       const float* __restrict__ gamma, const float* __restrict__ beta,
                       float* __restrict__ scl, float* __restrict__ shf)
{
    const int o = threadIdx.x;
    float s = 0.f, q = 0.f;
    for (int k = 0; k < NBUCKET; ++k) { s += bsum[k*CO + o]; q += bsq[k*CO + o]; }
    float mean = s / (float)NRED;
    float var  = q / (float)NRED - mean*mean;
    float rstd = rsqrtf(var + EPSV);
    float sc = gamma[o] * rstd;
    scl[o] = sc;
    shf[o] = beta[o] - mean * sc;
}

// ---------------------------------------------------------------------------
// K3: in-place normalize d_out, float4 coalesced (L3-resident)
// ---------------------------------------------------------------------------
__global__ __launch_bounds__(256) void agc_k3(
    float* __restrict__ out, const float* __restrict__ scl, const float* __restrict__ shf)
{
    const int n4 = NB*CO*TT*VV/4;
    float4* p = (float4*)out;
    for (int i = blockIdx.x*blockDim.x + threadIdx.x; i < n4; i += gridDim.x*blockDim.x) {
        int ch = (i / (TT*VV/4)) & (CO-1);
        float4 v = p[i];
        float sc = scl[ch], sh = shf[ch];
        v.x = fmaf(v.x, sc, sh);
        v.y = fmaf(v.y, sc, sh);
        v.z = fmaf(v.z, sc, sh);
        v.w = fmaf(v.w, sc, sh);
        p[i] = v;
    }
}

extern "C" void kernel_launch(void* const* d_in, const int* in_sizes, int n_in,
                              void* d_out, int out_size, void* d_ws, size_t ws_size,
                              hipStream_t stream) {
    const float* x     = (const float*)d_in[0];
    const float* tw    = (const float*)d_in[1];
    const float* tbb   = (const float*)d_in[2];
    const float* pw    = (const float*)d_in[3];
    const float* pbb   = (const float*)d_in[4];
    const float* gw    = (const float*)d_in[5];
    const float* gbb   = (const float*)d_in[6];
    const float* gamma = (const float*)d_in[7];
    const float* beta  = (const float*)d_in[8];
    float* out = (float*)d_out;
    float* ws  = (float*)d_ws;

    float* bsum = ws;                          // [64][128]
    float* bsq  = ws + NBUCKET*CO;             // [64][128]
    float* scl  = ws + 2*NBUCKET*CO;           // [128]
    float* shf  = ws + 2*NBUCKET*CO + CO;      // [128]
    ushort_t* twA = (ushort_t*)(ws + 2*NBUCKET*CO + 2*CO);   // 2048 bf16
    ushort_t* pwA = twA + 2048;                               // 2048 bf16
    ushort_t* gwB = twA + 4096;                               // 8192 bf16
    float* tbD = (float*)(gwB + 8192);                        // 1024 f32
    float* pbD = tbD + 1024;                                  // 1024 f32

    agc_k0<<<64, 256, 0, stream>>>(tw, pw, gw, tbb, pbb, twA, pwA, gwB, tbD, pbD, ws);
    agc_k1<<<NBLK, 256, 0, stream>>>(x, gbb, twA, pwA, gwB, tbD, pbD, out, bsum, bsq);
    agc_k2<<<1, CO, 0, stream>>>(bsum, bsq, gamma, beta, scl, shf);
    agc_k3<<<2048, 256, 0, stream>>>(out, scl, shf);
}